// Round 5
// baseline (652.825 us; speedup 1.0000x reference)
//
#include <hip/hip_runtime.h>
#include <cstdint>

// Problem constants (fixed by reference):
#define Bc 1024
#define Tc 4096
#define Nc 2048
#define Kc 16
#define Mc 65536

#define TILE_N 8                       // rows per gather block -> 2 MiB memory window
#define ADDR_BYTES ((size_t)Bc * Nc * sizeof(unsigned short))   // 4 MiB

// ---------------- Pass 1: per-b address computation ----------------
// One block per b. Ballot-pack input row into LDS bitset, compute 16-bit
// addresses for all 2048 n, store coalesced uint16 to addr[(B,N)].
__global__ __launch_bounds__(256) void addr_kernel(
    const int* __restrict__ input_bits,   // (B, T)
    const int* __restrict__ connections,  // (N, K)
    unsigned short* __restrict__ addr)    // (B, N) 16-bit addresses
{
    __shared__ uint32_t bits[Tc / 32];    // 512 B

    const int b    = blockIdx.x;
    const int tid  = threadIdx.x;
    const int lane = tid & 63;
    const int wave = tid >> 6;

    const int* row = input_bits + (size_t)b * Tc;

#pragma unroll
    for (int i = 0; i < Tc / 256; ++i) {
        const int pos = i * 256 + wave * 64 + lane;
        const unsigned long long m = __ballot(row[pos] & 1);
        if (lane == 0) {
            const int w64 = i * 4 + wave;
            bits[w64 * 2]     = (uint32_t)m;
            bits[w64 * 2 + 1] = (uint32_t)(m >> 32);
        }
    }
    __syncthreads();

#pragma unroll
    for (int i = 0; i < Nc / 256; ++i) {
        const int n = i * 256 + tid;
        const int4* cp = (const int4*)(connections + n * Kc);
        const int4 c0 = cp[0], c1 = cp[1], c2 = cp[2], c3 = cp[3];
        const int c[16] = {c0.x, c0.y, c0.z, c0.w,
                           c1.x, c1.y, c1.z, c1.w,
                           c2.x, c2.y, c2.z, c2.w,
                           c3.x, c3.y, c3.z, c3.w};
        uint32_t a = 0;
#pragma unroll
        for (int k = 0; k < 16; ++k) {
            const uint32_t t = (uint32_t)c[k];
            a |= ((bits[t >> 5] >> (t & 31)) & 1u) << k;
        }
        addr[(size_t)b * Nc + n] = (unsigned short)a;   // coalesced 2 B stores
    }
}

// ---------------- Pass 2: persistent per-tile gather ----------------
// grid = 256 blocks, one per 8-row tile of `memory` (2 MiB window, fits XCD L2).
// Each block handles ALL 1024 b for its tile: thread t covers b = t, t+256,
// t+512, t+768; 8 gathers per b = 32 independent loads/thread (deep MLP),
// all confined to the 2 MiB window -> DRAM page locality + L2 containment.
__global__ __launch_bounds__(256) void gather_kernel(
    const unsigned short* __restrict__ addr,  // (B, N)
    const int* __restrict__ memory,           // (N, M)
    int* __restrict__ out)                    // (B, N) bool-as-int32
{
    const int n0 = blockIdx.x * TILE_N;
    const int t  = threadIdx.x;

#pragma unroll
    for (int bi = 0; bi < 4; ++bi) {
        const int b = bi * 256 + t;

        // 8 uint16 addresses = 16 B contiguous.
        const int4 aw = *(const int4*)(addr + (size_t)b * Nc + n0);
        uint32_t a[TILE_N];
        a[0] = (uint32_t)aw.x & 0xFFFFu;  a[1] = (uint32_t)aw.x >> 16;
        a[2] = (uint32_t)aw.y & 0xFFFFu;  a[3] = (uint32_t)aw.y >> 16;
        a[4] = (uint32_t)aw.z & 0xFFFFu;  a[5] = (uint32_t)aw.z >> 16;
        a[6] = (uint32_t)aw.w & 0xFFFFu;  a[7] = (uint32_t)aw.w >> 16;

        // 8 independent gathers within rows n0..n0+7 (2 MiB window).
        int v[TILE_N];
#pragma unroll
        for (int k = 0; k < TILE_N; ++k) {
            v[k] = memory[((size_t)(n0 + k) << 16) + a[k]];
        }

        // 32 B contiguous store per (thread, b).
        int4* op = (int4*)(out + (size_t)b * Nc + n0);
        op[0] = make_int4(v[0] & 1, v[1] & 1, v[2] & 1, v[3] & 1);
        op[1] = make_int4(v[4] & 1, v[5] & 1, v[6] & 1, v[7] & 1);
    }
}

// ---------------- Fallback: single-pass direct (if ws too small) ----------------
__global__ __launch_bounds__(256) void ram_lookup_direct(
    const int* __restrict__ input_bits,
    const int* __restrict__ connections,
    const int* __restrict__ memory,
    int* __restrict__ out)
{
    __shared__ uint32_t bits[Tc / 32];
    const int b = blockIdx.x, tid = threadIdx.x;
    const int lane = tid & 63, wave = tid >> 6;
    const int* row = input_bits + (size_t)b * Tc;
#pragma unroll
    for (int i = 0; i < Tc / 256; ++i) {
        const int pos = i * 256 + wave * 64 + lane;
        const unsigned long long m = __ballot(row[pos] & 1);
        if (lane == 0) {
            const int w64 = i * 4 + wave;
            bits[w64 * 2] = (uint32_t)m;
            bits[w64 * 2 + 1] = (uint32_t)(m >> 32);
        }
    }
    __syncthreads();
#pragma unroll
    for (int i = 0; i < Nc / 256; ++i) {
        const int n = i * 256 + tid;
        const int4* cp = (const int4*)(connections + n * Kc);
        const int4 c0 = cp[0], c1 = cp[1], c2 = cp[2], c3 = cp[3];
        const int c[16] = {c0.x, c0.y, c0.z, c0.w, c1.x, c1.y, c1.z, c1.w,
                           c2.x, c2.y, c2.z, c2.w, c3.x, c3.y, c3.z, c3.w};
        uint32_t a = 0;
#pragma unroll
        for (int k = 0; k < 16; ++k) {
            const uint32_t t = (uint32_t)c[k];
            a |= ((bits[t >> 5] >> (t & 31)) & 1u) << k;
        }
        out[(size_t)b * Nc + n] = memory[(size_t)n * Mc + a] & 1;
    }
}

extern "C" void kernel_launch(void* const* d_in, const int* in_sizes, int n_in,
                              void* d_out, int out_size, void* d_ws, size_t ws_size,
                              hipStream_t stream) {
    const int* input_bits  = (const int*)d_in[0];  // B*T
    const int* connections = (const int*)d_in[1];  // N*K
    const int* memory      = (const int*)d_in[2];  // N*M
    int* out               = (int*)d_out;          // B*N (bool -> int32)

    if (ws_size >= ADDR_BYTES) {
        unsigned short* addr = (unsigned short*)d_ws;
        hipLaunchKernelGGL(addr_kernel, dim3(Bc), dim3(256), 0, stream,
                           input_bits, connections, addr);
        hipLaunchKernelGGL(gather_kernel, dim3(Nc / TILE_N), dim3(256), 0, stream,
                           addr, memory, out);
    } else {
        hipLaunchKernelGGL(ram_lookup_direct, dim3(Bc), dim3(256), 0, stream,
                           input_bits, connections, memory, out);
    }
}

// Round 6
// 623.312 us; speedup vs baseline: 1.0473x; 1.0473x over previous
//
#include <hip/hip_runtime.h>
#include <cstdint>

// Problem constants (fixed by reference):
#define Bc 1024
#define Tc 4096
#define Nc 2048
#define Kc 16
#define Mc 65536

// One block per batch row b (1024 blocks x 256 threads, 4 blocks/CU).
// Phase 1: ballot-pack input_bits[b,:] into a 4096-bit LDS bitset.
// Phase 2+3 fused: per n-group, compute the 16-bit address from 16 LDS bit
//   probes and IMMEDIATELY issue the (fully divergent) memory gather, so the
//   8 independent global loads overlap the remaining LDS probe work.
// Phase 4: coalesced int32 stores (bool output -> int32 in harness).
__global__ __launch_bounds__(256) void ram_lookup_fused(
    const int* __restrict__ input_bits,   // (B, T) int32 in {0,1}
    const int* __restrict__ connections,  // (N, K) int32 in [0, T)
    const int* __restrict__ memory,       // (N, M) int32
    int* __restrict__ out)                // (B, N) bool-as-int32
{
    __shared__ uint32_t bits[Tc / 32];    // 128 words = 512 B

    const int b    = blockIdx.x;
    const int tid  = threadIdx.x;
    const int lane = tid & 63;
    const int wave = tid >> 6;

    const int* row = input_bits + (size_t)b * Tc;

    // ---- Phase 1: build bitset via ballot ----
#pragma unroll
    for (int i = 0; i < Tc / 256; ++i) {          // 16 iterations
        const int pos = i * 256 + wave * 64 + lane;
        const unsigned long long m = __ballot(row[pos] & 1);
        if (lane == 0) {
            const int w64 = i * 4 + wave;
            bits[w64 * 2]     = (uint32_t)m;
            bits[w64 * 2 + 1] = (uint32_t)(m >> 32);
        }
    }
    __syncthreads();

    // ---- Phase 2+3 fused: addr -> immediate gather (8 independent chains) ----
    int vals[Nc / 256];
#pragma unroll
    for (int i = 0; i < Nc / 256; ++i) {          // 8 iterations
        const int n = i * 256 + tid;
        const int4* cp = (const int4*)(connections + n * Kc);
        const int4 c0 = cp[0], c1 = cp[1], c2 = cp[2], c3 = cp[3];
        const int c[16] = {c0.x, c0.y, c0.z, c0.w,
                           c1.x, c1.y, c1.z, c1.w,
                           c2.x, c2.y, c2.z, c2.w,
                           c3.x, c3.y, c3.z, c3.w};
        uint32_t a = 0;
#pragma unroll
        for (int k = 0; k < 16; ++k) {
            const uint32_t t = (uint32_t)c[k];
            a |= ((bits[t >> 5] >> (t & 31)) & 1u) << k;
        }
        // Issue the gather now; loads from successive i-iterations overlap.
        vals[i] = __builtin_nontemporal_load(memory + ((size_t)n << 16) + a);
    }

    // ---- Phase 4: coalesced stores ----
#pragma unroll
    for (int i = 0; i < Nc / 256; ++i) {
        __builtin_nontemporal_store(vals[i] & 1,
                                    out + (size_t)b * Nc + i * 256 + tid);
    }
}

extern "C" void kernel_launch(void* const* d_in, const int* in_sizes, int n_in,
                              void* d_out, int out_size, void* d_ws, size_t ws_size,
                              hipStream_t stream) {
    const int* input_bits  = (const int*)d_in[0];  // B*T
    const int* connections = (const int*)d_in[1];  // N*K
    const int* memory      = (const int*)d_in[2];  // N*M
    int* out               = (int*)d_out;          // B*N (bool -> int32)

    hipLaunchKernelGGL(ram_lookup_fused, dim3(Bc), dim3(256), 0, stream,
                       input_bits, connections, memory, out);
}